// Round 2
// baseline (575.311 us; speedup 1.0000x reference)
//
#include <hip/hip_runtime.h>
#include <stdint.h>

#define BB 16
#define LSEQ 8192
#define DD 512
#define PER 64
#define NBLK 128
#define QSCALE 0.45f

typedef __attribute__((ext_vector_type(8))) short short8;
typedef __attribute__((ext_vector_type(4))) float f32x4;
typedef unsigned short ushort_t;

__device__ __forceinline__ ushort_t f2bf(float f) {
    union { float f; uint32_t u; } c; c.f = f;
    uint32_t u = c.u + 0x7FFFu + ((c.u >> 16) & 1u);
    return (ushort_t)(u >> 16);
}
__device__ __forceinline__ float bf2f(ushort_t h) {
    union { float f; uint32_t u; } c; c.u = ((uint32_t)h) << 16;
    return c.f;
}

// ---------------- K_t1: [B,L,D] fp32 -> [B,D,L] bf16 (optionally scaled) ----
__global__ __launch_bounds__(256) void kt1(const float* __restrict__ src,
                                           ushort_t* __restrict__ dst,
                                           float scale) {
    __shared__ ushort_t tile[64][68];
    const int t = threadIdx.x;
    const int l0 = blockIdx.x * 64, d0 = blockIdx.y * 64, b = blockIdx.z;
    const float* sp = src + (size_t)b * LSEQ * DD;
    const int tr = t >> 4, tc = (t & 15) * 4;
#pragma unroll
    for (int i = 0; i < 4; ++i) {
        int row = i * 16 + tr;  // l offset
        float4 v = *(const float4*)(sp + (size_t)(l0 + row) * DD + d0 + tc);
        ushort_t* p = &tile[row][tc];
        p[0] = f2bf(v.x * scale); p[1] = f2bf(v.y * scale);
        p[2] = f2bf(v.z * scale); p[3] = f2bf(v.w * scale);
    }
    __syncthreads();
    ushort_t* dp = dst + (size_t)b * DD * LSEQ;
#pragma unroll
    for (int i = 0; i < 4; ++i) {
        int drow = i * 16 + tr;  // d offset
        uint32_t w0 = (uint32_t)tile[tc + 0][drow] | ((uint32_t)tile[tc + 1][drow] << 16);
        uint32_t w1 = (uint32_t)tile[tc + 2][drow] | ((uint32_t)tile[tc + 3][drow] << 16);
        *(uint2*)(dp + (size_t)(d0 + drow) * LSEQ + l0 + tc) = make_uint2(w0, w1);
    }
}

// ---------------- K_t2: v [B,L,D] fp32 -> vTT [B,D,PER,NBLK] bf16 -----------
__global__ __launch_bounds__(256) void kt2(const float* __restrict__ v,
                                           ushort_t* __restrict__ vtt) {
    __shared__ __align__(16) ushort_t sm[64 * 264];  // [p][di*16+mi], p-stride 264
    const int t = threadIdx.x;
    const int m0 = blockIdx.x * 16, d0 = blockIdx.y * 16, b = blockIdx.z;
    const float* vp = v + (size_t)b * LSEQ * DD;
#pragma unroll
    for (int it = 0; it < 16; ++it) {
        int pp = it * 4 + (t >> 6);
        int mi = (t >> 2) & 15;
        int diq = (t & 3) * 4;
        float4 x = *(const float4*)(vp + (size_t)((m0 + mi) * PER + pp) * DD + d0 + diq);
        ushort_t* s = &sm[pp * 264 + diq * 16 + mi];
        s[0]  = f2bf(x.x);
        s[16] = f2bf(x.y);
        s[32] = f2bf(x.z);
        s[48] = f2bf(x.w);
    }
    __syncthreads();
#pragma unroll
    for (int it = 0; it < 4; ++it) {
        int di = t >> 4;
        int p  = (t & 15) + it * 16;
        const ushort_t* s = &sm[p * 264 + di * 16];
        uint4 a = *(const uint4*)s;
        uint4 b2 = *(const uint4*)(s + 8);
        ushort_t* op = vtt + (size_t)(((size_t)(b * DD + d0 + di) * PER + p) * NBLK + m0);
        *(uint4*)op = a;
        *(uint4*)(op + 8) = b2;
    }
}

// ---------------- K_att: per-(b,d) attention with MFMA ----------------------
// Qs/Ks: [128 rows][64 p]  (row stride 64 elem = 8 granules of 16B)
// Vs:    [64 p rows][128 m] (row stride 128 elem = 16 granules)
// Ps:    [128 n rows][128 m]
// XOR swizzle: granule' = granule ^ (row & 7)
__global__ __launch_bounds__(256) void katt(const ushort_t* __restrict__ qT,
                                            const ushort_t* __restrict__ kT,
                                            const ushort_t* __restrict__ vTT,
                                            float* __restrict__ attn,
                                            ushort_t* __restrict__ outT) {
    __shared__ __align__(16) ushort_t sm[40960];
    ushort_t* Qs = sm;
    ushort_t* Ks = sm + 8192;
    ushort_t* Vs = sm + 16384;
    ushort_t* Ps = sm + 24576;

    const int t = threadIdx.x;
    const int bd = blockIdx.x;
    const size_t base = (size_t)bd * 8192;
    const ushort_t* qp = qT + base;
    const ushort_t* kp = kT + base;
    const ushort_t* vp = vTT + base;

    // stage Q, K, V tiles (swizzled)
#pragma unroll
    for (int it = 0; it < 4; ++it) {
        int e = it * 2048 + t * 8;
        int n = e >> 6, pc = (e >> 3) & 7;
        int gq = pc ^ (n & 7);
        *(short8*)&Qs[n * 64 + gq * 8] = *(const short8*)(qp + e);
        *(short8*)&Ks[n * 64 + gq * 8] = *(const short8*)(kp + e);
        int p = e >> 7, mc = (e >> 3) & 15;
        int gv = mc ^ (p & 7);
        *(short8*)&Vs[p * 128 + gv * 8] = *(const short8*)(vp + e);
    }
    __syncthreads();

    const int lane = t & 63, w = t >> 6;
    const int lrow = lane & 15, lquad = lane >> 4;

    // ---- S = Q' K'^T : rows n in [w*32, w*32+32) ----
    f32x4 acc[2][8];
#pragma unroll
    for (int nt = 0; nt < 2; ++nt)
#pragma unroll
        for (int mt = 0; mt < 8; ++mt) acc[nt][mt] = (f32x4){0.f, 0.f, 0.f, 0.f};

    short8 aQ[2][2];
#pragma unroll
    for (int nt = 0; nt < 2; ++nt) {
        int n = w * 32 + nt * 16 + lrow;
#pragma unroll
        for (int s = 0; s < 2; ++s) {
            int g = (s * 4 + lquad) ^ (n & 7);
            aQ[nt][s] = *(const short8*)&Qs[n * 64 + g * 8];
        }
    }
#pragma unroll
    for (int mt = 0; mt < 8; ++mt) {
        int m = mt * 16 + lrow;
#pragma unroll
        for (int s = 0; s < 2; ++s) {
            int g = (s * 4 + lquad) ^ (m & 7);
            short8 bK = *(const short8*)&Ks[m * 64 + g * 8];
#pragma unroll
            for (int nt = 0; nt < 2; ++nt)
                acc[nt][mt] = __builtin_amdgcn_mfma_f32_16x16x32_bf16(aQ[nt][s], bK, acc[nt][mt], 0, 0, 0);
        }
    }

    // ---- softmax over m (rows are per (lquad, reg); cols across 16 lanes + 8 mt) ----
    float* attnp = attn + (size_t)bd * (NBLK * NBLK);
#pragma unroll
    for (int nt = 0; nt < 2; ++nt) {
        int nbase = w * 32 + nt * 16;
#pragma unroll
        for (int r = 0; r < 4; ++r) {
            int row = nbase + lquad * 4 + r;
            float pv[8];
            float mx = -1e30f;
#pragma unroll
            for (int mt = 0; mt < 8; ++mt) { pv[mt] = acc[nt][mt][r]; mx = fmaxf(mx, pv[mt]); }
#pragma unroll
            for (int msk = 1; msk < 16; msk <<= 1) mx = fmaxf(mx, __shfl_xor(mx, msk, 64));
            float sum = 0.f;
#pragma unroll
            for (int mt = 0; mt < 8; ++mt) {
                pv[mt] = exp2f((pv[mt] - mx) * 1.4426950408889634f);
                sum += pv[mt];
            }
#pragma unroll
            for (int msk = 1; msk < 16; msk <<= 1) sum += __shfl_xor(sum, msk, 64);
            float inv = 1.0f / sum;
#pragma unroll
            for (int mt = 0; mt < 8; ++mt) {
                float a = pv[mt] * inv;
                int m = mt * 16 + lrow;
                attnp[(size_t)row * NBLK + m] = a;
                int g = (m >> 3) ^ (row & 7);
                Ps[row * 128 + g * 8 + (m & 7)] = f2bf(a);
            }
        }
    }
    __syncthreads();  // safety: ensure P writes visible (same-wave rows, but cheap)

    // ---- O = A V' : [128 n x 64 p], K over m=128 ----
    f32x4 oacc[2][4];
#pragma unroll
    for (int nt = 0; nt < 2; ++nt)
#pragma unroll
        for (int pt = 0; pt < 4; ++pt) oacc[nt][pt] = (f32x4){0.f, 0.f, 0.f, 0.f};

#pragma unroll
    for (int s = 0; s < 4; ++s) {
        short8 aP[2];
#pragma unroll
        for (int nt = 0; nt < 2; ++nt) {
            int n = w * 32 + nt * 16 + lrow;
            int g = (s * 4 + lquad) ^ (n & 7);
            aP[nt] = *(const short8*)&Ps[n * 128 + g * 8];
        }
#pragma unroll
        for (int pt = 0; pt < 4; ++pt) {
            int prow = pt * 16 + lrow;
            int gv = (s * 4 + lquad) ^ (prow & 7);
            short8 bV = *(const short8*)&Vs[prow * 128 + gv * 8];
#pragma unroll
            for (int nt = 0; nt < 2; ++nt)
                oacc[nt][pt] = __builtin_amdgcn_mfma_f32_16x16x32_bf16(aP[nt], bV, oacc[nt][pt], 0, 0, 0);
        }
    }

    ushort_t* op = outT + base;
#pragma unroll
    for (int nt = 0; nt < 2; ++nt)
#pragma unroll
        for (int pt = 0; pt < 4; ++pt)
#pragma unroll
            for (int r = 0; r < 4; ++r) {
                int row = w * 32 + nt * 16 + lquad * 4 + r;
                int p = pt * 16 + lrow;
                op[row * PER + p] = f2bf(oacc[nt][pt][r]);
            }
}

// ---------------- K_o: outT [B,D,L] bf16 -> out [B,L,D] fp32 ----------------
__global__ __launch_bounds__(256) void ko(const ushort_t* __restrict__ outT,
                                          float* __restrict__ out) {
    __shared__ ushort_t tile[64][68];  // [d][l]
    const int t = threadIdx.x;
    const int l0 = blockIdx.x * 64, d0 = blockIdx.y * 64, b = blockIdx.z;
    const ushort_t* sp = outT + (size_t)b * DD * LSEQ;
    const int tr = t >> 4, tc = (t & 15) * 4;
#pragma unroll
    for (int i = 0; i < 4; ++i) {
        int drow = i * 16 + tr;
        uint2 vv = *(const uint2*)(sp + (size_t)(d0 + drow) * LSEQ + l0 + tc);
        ushort_t* p = &tile[drow][tc];
        p[0] = (ushort_t)(vv.x & 0xffffu); p[1] = (ushort_t)(vv.x >> 16);
        p[2] = (ushort_t)(vv.y & 0xffffu); p[3] = (ushort_t)(vv.y >> 16);
    }
    __syncthreads();
    float* opB = out + (size_t)b * LSEQ * DD;
#pragma unroll
    for (int i = 0; i < 4; ++i) {
        int lr = i * 16 + tr;
        float4 v;
        v.x = bf2f(tile[tc + 0][lr]); v.y = bf2f(tile[tc + 1][lr]);
        v.z = bf2f(tile[tc + 2][lr]); v.w = bf2f(tile[tc + 3][lr]);
        *(float4*)(opB + (size_t)(l0 + lr) * DD + d0 + tc) = v;
    }
}

extern "C" void kernel_launch(void* const* d_in, const int* in_sizes, int n_in,
                              void* d_out, int out_size, void* d_ws, size_t ws_size,
                              hipStream_t stream) {
    const float* q = (const float*)d_in[0];
    const float* k = (const float*)d_in[1];
    const float* v = (const float*)d_in[2];
    float* outp = (float*)d_out;
    float* attnp = outp + (size_t)BB * LSEQ * DD;

    ushort_t* qT  = (ushort_t*)d_ws;
    ushort_t* kT  = qT  + (size_t)BB * DD * LSEQ;
    ushort_t* vTT = kT  + (size_t)BB * DD * LSEQ;
    ushort_t* oT  = vTT + (size_t)BB * DD * LSEQ;

    dim3 g1(LSEQ / 64, DD / 64, BB);
    kt1<<<g1, 256, 0, stream>>>(q, qT, QSCALE);
    kt1<<<g1, 256, 0, stream>>>(k, kT, 1.0f);
    dim3 g2(NBLK / 16, DD / 16, BB);
    kt2<<<g2, 256, 0, stream>>>(v, vTT);
    katt<<<dim3(BB * DD), 256, 0, stream>>>(qT, kT, vTT, attnp, oT);
    ko<<<g1, 256, 0, stream>>>(oT, outp);
}

// Round 4
// 548.878 us; speedup vs baseline: 1.0482x; 1.0482x over previous
//
#include <hip/hip_runtime.h>
#include <stdint.h>

#define BB 16
#define LSEQ 8192
#define DD 512
#define PER 64
#define NBLK 128
#define QSCALE 0.45f

typedef __attribute__((ext_vector_type(8))) short short8;
typedef __attribute__((ext_vector_type(4))) float f32x4;
typedef __attribute__((ext_vector_type(2))) unsigned int uint2v;
typedef unsigned short ushort_t;

__device__ __forceinline__ ushort_t f2bf(float f) {
    union { float f; uint32_t u; } c; c.f = f;
    uint32_t u = c.u + 0x7FFFu + ((c.u >> 16) & 1u);
    return (ushort_t)(u >> 16);
}
__device__ __forceinline__ float bf2f(ushort_t h) {
    union { float f; uint32_t u; } c; c.u = ((uint32_t)h) << 16;
    return c.f;
}

// ---- K_t1: q AND k [B,L,D] fp32 -> qT,kT [B,D,L] bf16 (q scaled by 0.45) ---
// NT loads (inputs are dead after this); cached stores (read by katt soon).
__global__ __launch_bounds__(256) void kt1(const float* __restrict__ q,
                                           const float* __restrict__ k,
                                           ushort_t* __restrict__ qT,
                                           ushort_t* __restrict__ kT) {
    __shared__ ushort_t tile[64][72];  // row stride 144B: 16-lane read = 2-way bank (free)
    const int t = threadIdx.x;
    const int zz = blockIdx.z;
    const int b = zz & (BB - 1);
    const bool isk = zz >= BB;
    const float scale = isk ? 1.0f : QSCALE;
    const float* sp = (isk ? k : q) + (size_t)b * LSEQ * DD;
    ushort_t* dp = (isk ? kT : qT) + (size_t)b * DD * LSEQ;
    const int l0 = blockIdx.x * 64, d0 = blockIdx.y * 64;
    const int tr = t >> 4, tc = (t & 15) * 4;
#pragma unroll
    for (int i = 0; i < 4; ++i) {
        int row = i * 16 + tr;  // l offset
        f32x4 v = __builtin_nontemporal_load(
            (const f32x4*)(sp + (size_t)(l0 + row) * DD + d0 + tc));
        ushort_t* p = &tile[row][tc];
        p[0] = f2bf(v[0] * scale); p[1] = f2bf(v[1] * scale);
        p[2] = f2bf(v[2] * scale); p[3] = f2bf(v[3] * scale);
    }
    __syncthreads();
#pragma unroll
    for (int i = 0; i < 4; ++i) {
        int drow = i * 16 + tr;  // d offset
        uint32_t w0 = (uint32_t)tile[tc + 0][drow] | ((uint32_t)tile[tc + 1][drow] << 16);
        uint32_t w1 = (uint32_t)tile[tc + 2][drow] | ((uint32_t)tile[tc + 3][drow] << 16);
        uint2v wv; wv[0] = w0; wv[1] = w1;
        *(uint2v*)(dp + (size_t)(d0 + drow) * LSEQ + l0 + tc) = wv;
    }
}

// ---------------- K_t2: v [B,L,D] fp32 -> vTT [B,D,PER,NBLK] bf16 -----------
__global__ __launch_bounds__(256) void kt2(const float* __restrict__ v,
                                           ushort_t* __restrict__ vtt) {
    __shared__ __align__(16) ushort_t sm[64 * 264];  // [p][di*16+mi], p-stride 264
    const int t = threadIdx.x;
    const int m0 = blockIdx.x * 16, d0 = blockIdx.y * 16, b = blockIdx.z;
    const float* vp = v + (size_t)b * LSEQ * DD;
#pragma unroll
    for (int it = 0; it < 16; ++it) {
        int pp = it * 4 + (t >> 6);
        int mi = (t >> 2) & 15;
        int diq = (t & 3) * 4;
        f32x4 x = __builtin_nontemporal_load(
            (const f32x4*)(vp + (size_t)((m0 + mi) * PER + pp) * DD + d0 + diq));
        ushort_t* s = &sm[pp * 264 + diq * 16 + mi];
        s[0]  = f2bf(x[0]);
        s[16] = f2bf(x[1]);
        s[32] = f2bf(x[2]);
        s[48] = f2bf(x[3]);
    }
    __syncthreads();
#pragma unroll
    for (int it = 0; it < 4; ++it) {
        int di = t >> 4;
        int p  = (t & 15) + it * 16;
        const ushort_t* s = &sm[p * 264 + di * 16];
        short8 a = *(const short8*)s;
        short8 b2 = *(const short8*)(s + 8);
        ushort_t* op = vtt + (size_t)(((size_t)(b * DD + d0 + di) * PER + p) * NBLK + m0);
        *(short8*)op = a;       // cached: read by katt
        *(short8*)(op + 8) = b2;
    }
}

// ---------------- K_att: per-(b,d) attention with MFMA ----------------------
// Qs/Ks: [128 rows][64 p]  (row stride 64 elem = 8 granules of 16B)
// Vs:    [64 p rows][128 m] (row stride 128 elem = 16 granules)
// Ps:    [128 n rows][128 m]
// XOR swizzle: granule' = granule ^ (row & 7)
// NT: reads of qT/kT/vTT (dead after), stores of attn (never re-read).
// oT stores stay cached (read by ko next).
__global__ __launch_bounds__(256) void katt(const ushort_t* __restrict__ qT,
                                            const ushort_t* __restrict__ kT,
                                            const ushort_t* __restrict__ vTT,
                                            float* __restrict__ attn,
                                            ushort_t* __restrict__ outT) {
    __shared__ __align__(16) ushort_t sm[40960];
    ushort_t* Qs = sm;
    ushort_t* Ks = sm + 8192;
    ushort_t* Vs = sm + 16384;
    ushort_t* Ps = sm + 24576;

    const int t = threadIdx.x;
    const int bd = blockIdx.x;
    const size_t base = (size_t)bd * 8192;
    const ushort_t* qp = qT + base;
    const ushort_t* kp = kT + base;
    const ushort_t* vp = vTT + base;

    // stage Q, K, V tiles (swizzled)
#pragma unroll
    for (int it = 0; it < 4; ++it) {
        int e = it * 2048 + t * 8;
        int n = e >> 6, pc = (e >> 3) & 7;
        int gq = pc ^ (n & 7);
        *(short8*)&Qs[n * 64 + gq * 8] = __builtin_nontemporal_load((const short8*)(qp + e));
        *(short8*)&Ks[n * 64 + gq * 8] = __builtin_nontemporal_load((const short8*)(kp + e));
        int p = e >> 7, mc = (e >> 3) & 15;
        int gv = mc ^ (p & 7);
        *(short8*)&Vs[p * 128 + gv * 8] = __builtin_nontemporal_load((const short8*)(vp + e));
    }
    __syncthreads();

    const int lane = t & 63, w = t >> 6;
    const int lrow = lane & 15, lquad = lane >> 4;

    // ---- S = Q' K'^T : rows n in [w*32, w*32+32) ----
    f32x4 acc[2][8];
#pragma unroll
    for (int nt = 0; nt < 2; ++nt)
#pragma unroll
        for (int mt = 0; mt < 8; ++mt) acc[nt][mt] = (f32x4){0.f, 0.f, 0.f, 0.f};

    short8 aQ[2][2];
#pragma unroll
    for (int nt = 0; nt < 2; ++nt) {
        int n = w * 32 + nt * 16 + lrow;
#pragma unroll
        for (int s = 0; s < 2; ++s) {
            int g = (s * 4 + lquad) ^ (n & 7);
            aQ[nt][s] = *(const short8*)&Qs[n * 64 + g * 8];
        }
    }
#pragma unroll
    for (int mt = 0; mt < 8; ++mt) {
        int m = mt * 16 + lrow;
#pragma unroll
        for (int s = 0; s < 2; ++s) {
            int g = (s * 4 + lquad) ^ (m & 7);
            short8 bK = *(const short8*)&Ks[m * 64 + g * 8];
#pragma unroll
            for (int nt = 0; nt < 2; ++nt)
                acc[nt][mt] = __builtin_amdgcn_mfma_f32_16x16x32_bf16(aQ[nt][s], bK, acc[nt][mt], 0, 0, 0);
        }
    }

    // ---- softmax over m (rows are per (lquad, reg); cols across 16 lanes + 8 mt) ----
    float* attnp = attn + (size_t)bd * (NBLK * NBLK);
#pragma unroll
    for (int nt = 0; nt < 2; ++nt) {
        int nbase = w * 32 + nt * 16;
#pragma unroll
        for (int r = 0; r < 4; ++r) {
            int row = nbase + lquad * 4 + r;
            float pv[8];
            float mx = -1e30f;
#pragma unroll
            for (int mt = 0; mt < 8; ++mt) { pv[mt] = acc[nt][mt][r]; mx = fmaxf(mx, pv[mt]); }
#pragma unroll
            for (int msk = 1; msk < 16; msk <<= 1) mx = fmaxf(mx, __shfl_xor(mx, msk, 64));
            float sum = 0.f;
#pragma unroll
            for (int mt = 0; mt < 8; ++mt) {
                pv[mt] = exp2f((pv[mt] - mx) * 1.4426950408889634f);
                sum += pv[mt];
            }
#pragma unroll
            for (int msk = 1; msk < 16; msk <<= 1) sum += __shfl_xor(sum, msk, 64);
            float inv = 1.0f / sum;
#pragma unroll
            for (int mt = 0; mt < 8; ++mt) {
                float a = pv[mt] * inv;
                int m = mt * 16 + lrow;
                __builtin_nontemporal_store(a, attnp + (size_t)row * NBLK + m);
                int g = (m >> 3) ^ (row & 7);
                Ps[row * 128 + g * 8 + (m & 7)] = f2bf(a);
            }
        }
    }
    __syncthreads();  // cheap safety barrier (wave-private rows in practice)

    // ---- O = A V' : [128 n x 64 p], K over m=128 ----
    f32x4 oacc[2][4];
#pragma unroll
    for (int nt = 0; nt < 2; ++nt)
#pragma unroll
        for (int pt = 0; pt < 4; ++pt) oacc[nt][pt] = (f32x4){0.f, 0.f, 0.f, 0.f};

#pragma unroll
    for (int s = 0; s < 4; ++s) {
        short8 aP[2];
#pragma unroll
        for (int nt = 0; nt < 2; ++nt) {
            int n = w * 32 + nt * 16 + lrow;
            int g = (s * 4 + lquad) ^ (n & 7);
            aP[nt] = *(const short8*)&Ps[n * 128 + g * 8];
        }
#pragma unroll
        for (int pt = 0; pt < 4; ++pt) {
            int prow = pt * 16 + lrow;
            int gv = (s * 4 + lquad) ^ (prow & 7);
            short8 bV = *(const short8*)&Vs[prow * 128 + gv * 8];
#pragma unroll
            for (int nt = 0; nt < 2; ++nt)
                oacc[nt][pt] = __builtin_amdgcn_mfma_f32_16x16x32_bf16(aP[nt], bV, oacc[nt][pt], 0, 0, 0);
        }
    }

    ushort_t* op = outT + base;
#pragma unroll
    for (int nt = 0; nt < 2; ++nt)
#pragma unroll
        for (int pt = 0; pt < 4; ++pt)
#pragma unroll
            for (int r = 0; r < 4; ++r) {
                int row = w * 32 + nt * 16 + lquad * 4 + r;
                int p = pt * 16 + lrow;
                op[row * PER + p] = f2bf(oacc[nt][pt][r]);  // cached: read by ko
            }
}

// ---------------- K_o: outT [B,D,L] bf16 -> out [B,L,D] fp32 ----------------
// NT: oT read (dead after), out store (never re-read).
__global__ __launch_bounds__(256) void ko(const ushort_t* __restrict__ outT,
                                          float* __restrict__ out) {
    __shared__ ushort_t tile[64][72];  // [d][l], padded row stride
    const int t = threadIdx.x;
    const int l0 = blockIdx.x * 64, d0 = blockIdx.y * 64, b = blockIdx.z;
    const ushort_t* sp = outT + (size_t)b * DD * LSEQ;
    const int tr = t >> 4, tc = (t & 15) * 4;
#pragma unroll
    for (int i = 0; i < 4; ++i) {
        int drow = i * 16 + tr;
        uint2v vv = __builtin_nontemporal_load(
            (const uint2v*)(sp + (size_t)(d0 + drow) * LSEQ + l0 + tc));
        ushort_t* p = &tile[drow][tc];
        p[0] = (ushort_t)(vv[0] & 0xffffu); p[1] = (ushort_t)(vv[0] >> 16);
        p[2] = (ushort_t)(vv[1] & 0xffffu); p[3] = (ushort_t)(vv[1] >> 16);
    }
    __syncthreads();
    float* opB = out + (size_t)b * LSEQ * DD;
#pragma unroll
    for (int i = 0; i < 4; ++i) {
        int lr = i * 16 + tr;
        f32x4 v;
        v[0] = bf2f(tile[tc + 0][lr]); v[1] = bf2f(tile[tc + 1][lr]);
        v[2] = bf2f(tile[tc + 2][lr]); v[3] = bf2f(tile[tc + 3][lr]);
        __builtin_nontemporal_store(v, (f32x4*)(opB + (size_t)(l0 + lr) * DD + d0 + tc));
    }
}

extern "C" void kernel_launch(void* const* d_in, const int* in_sizes, int n_in,
                              void* d_out, int out_size, void* d_ws, size_t ws_size,
                              hipStream_t stream) {
    const float* q = (const float*)d_in[0];
    const float* k = (const float*)d_in[1];
    const float* v = (const float*)d_in[2];
    float* outp = (float*)d_out;
    float* attnp = outp + (size_t)BB * LSEQ * DD;

    ushort_t* qT  = (ushort_t*)d_ws;
    ushort_t* kT  = qT  + (size_t)BB * DD * LSEQ;
    ushort_t* vTT = kT  + (size_t)BB * DD * LSEQ;
    ushort_t* oT  = vTT + (size_t)BB * DD * LSEQ;

    dim3 g1(LSEQ / 64, DD / 64, BB * 2);
    kt1<<<g1, 256, 0, stream>>>(q, k, qT, kT);
    dim3 g2(NBLK / 16, DD / 16, BB);
    kt2<<<g2, 256, 0, stream>>>(v, vTT);
    katt<<<dim3(BB * DD), 256, 0, stream>>>(qT, kT, vTT, attnp, oT);
    dim3 g3(LSEQ / 64, DD / 64, BB);
    ko<<<g3, 256, 0, stream>>>(oT, outp);
}

// Round 5
// 511.892 us; speedup vs baseline: 1.1239x; 1.0723x over previous
//
#include <hip/hip_runtime.h>
#include <stdint.h>

#define BB 16
#define LSEQ 8192
#define DD 512
#define PER 64
#define NBLK 128
#define QSCALE 0.45f

typedef __attribute__((ext_vector_type(8))) short short8;
typedef __attribute__((ext_vector_type(4))) float f32x4;
typedef __attribute__((ext_vector_type(2))) unsigned int uint2v;
typedef unsigned short ushort_t;

__device__ __forceinline__ ushort_t f2bf(float f) {
    union { float f; uint32_t u; } c; c.f = f;
    uint32_t u = c.u + 0x7FFFu + ((c.u >> 16) & 1u);
    return (ushort_t)(u >> 16);
}
__device__ __forceinline__ float bf2f(ushort_t h) {
    union { float f; uint32_t u; } c; c.u = ((uint32_t)h) << 16;
    return c.f;
}
__device__ __forceinline__ uint32_t pk2(float a, float b) {
    return (uint32_t)f2bf(a) | ((uint32_t)f2bf(b) << 16);
}

// ---- K_t1: q AND k [B,L,D] fp32 -> qT,kT [B,D,L] bf16 (q scaled by 0.45) ---
// LDS-free: each thread transposes a 4x4 (l x d) register subtile.
// Loads: 16 rows x 256B bursts; stores: 16 rows x 128B bursts. All coalesced.
__global__ __launch_bounds__(256) void kt1(const float* __restrict__ q,
                                           const float* __restrict__ k,
                                           ushort_t* __restrict__ qT,
                                           ushort_t* __restrict__ kT) {
    const int t = threadIdx.x;
    const int zz = blockIdx.z;
    const int b = zz & (BB - 1);
    const bool isk = zz >= BB;
    const float scale = isk ? 1.0f : QSCALE;
    const float* sp = (isk ? k : q) + (size_t)b * LSEQ * DD;
    ushort_t* dp = (isk ? kT : qT) + (size_t)b * DD * LSEQ;
    const int l0 = blockIdx.x * 64 + 4 * (t & 15);
    const int d0 = blockIdx.y * 64 + 4 * (t >> 4);
    f32x4 v[4];
#pragma unroll
    for (int j = 0; j < 4; ++j)
        v[j] = __builtin_nontemporal_load(
            (const f32x4*)(sp + (size_t)(l0 + j) * DD + d0));
#pragma unroll
    for (int dj = 0; dj < 4; ++dj) {
        uint2v w;
        w[0] = pk2(v[0][dj] * scale, v[1][dj] * scale);
        w[1] = pk2(v[2][dj] * scale, v[3][dj] * scale);
        *(uint2v*)(dp + (size_t)(d0 + dj) * LSEQ + l0) = w;  // cached: read by katt
    }
}

// ---- K_t2: v [B,L,D] fp32 -> vTT [B,D,PER,NBLK] bf16, LDS-free ------------
// Thread subtile: 4 d x 4 m at fixed p. vtt[((b*D+d)*PER+p)*NBLK+m] = v[b,m*64+p,d]
__global__ __launch_bounds__(256) void kt2(const float* __restrict__ v,
                                           ushort_t* __restrict__ vtt) {
    const int t = threadIdx.x;
    const int p  = blockIdx.x & 63;
    const int mh = blockIdx.x >> 6;  // 0..1
    const int m0 = mh * 64 + 4 * (t & 15);
    const int d0 = blockIdx.y * 64 + 4 * (t >> 4);
    const int b = blockIdx.z;
    const float* vp = v + (size_t)b * LSEQ * DD;
    f32x4 x[4];
#pragma unroll
    for (int mj = 0; mj < 4; ++mj)
        x[mj] = __builtin_nontemporal_load(
            (const f32x4*)(vp + (size_t)((m0 + mj) * PER + p) * DD + d0));
#pragma unroll
    for (int dj = 0; dj < 4; ++dj) {
        uint2v w;
        w[0] = pk2(x[0][dj], x[1][dj]);
        w[1] = pk2(x[2][dj], x[3][dj]);
        *(uint2v*)(vtt + (size_t)((size_t)(b * DD + d0 + dj) * PER + p) * NBLK + m0) = w;
    }
}

// ---------------- K_att: per-(b,d) attention with MFMA ----------------------
// Qs/Ks: [128 rows][64 p]  (row stride 64 elem = 8 granules of 16B)
// Vs:    [64 p rows][128 m] (row stride 128 elem = 16 granules)
// Ps:    [128 n rows][128 m]
// XOR swizzle: granule' = granule ^ (row & 7)
__global__ __launch_bounds__(256) void katt(const ushort_t* __restrict__ qT,
                                            const ushort_t* __restrict__ kT,
                                            const ushort_t* __restrict__ vTT,
                                            float* __restrict__ attn,
                                            ushort_t* __restrict__ outT) {
    __shared__ __align__(16) ushort_t sm[40960];
    ushort_t* Qs = sm;
    ushort_t* Ks = sm + 8192;
    ushort_t* Vs = sm + 16384;
    ushort_t* Ps = sm + 24576;

    const int t = threadIdx.x;
    const int bd = blockIdx.x;
    const size_t base = (size_t)bd * 8192;
    const ushort_t* qp = qT + base;
    const ushort_t* kp = kT + base;
    const ushort_t* vp = vTT + base;

    // stage Q, K, V tiles (swizzled)
#pragma unroll
    for (int it = 0; it < 4; ++it) {
        int e = it * 2048 + t * 8;
        int n = e >> 6, pc = (e >> 3) & 7;
        int gq = pc ^ (n & 7);
        *(short8*)&Qs[n * 64 + gq * 8] = __builtin_nontemporal_load((const short8*)(qp + e));
        *(short8*)&Ks[n * 64 + gq * 8] = __builtin_nontemporal_load((const short8*)(kp + e));
        int p = e >> 7, mc = (e >> 3) & 15;
        int gv = mc ^ (p & 7);
        *(short8*)&Vs[p * 128 + gv * 8] = __builtin_nontemporal_load((const short8*)(vp + e));
    }
    __syncthreads();

    const int lane = t & 63, w = t >> 6;
    const int lrow = lane & 15, lquad = lane >> 4;

    // ---- S = Q' K'^T : rows n in [w*32, w*32+32) ----
    f32x4 acc[2][8];
#pragma unroll
    for (int nt = 0; nt < 2; ++nt)
#pragma unroll
        for (int mt = 0; mt < 8; ++mt) acc[nt][mt] = (f32x4){0.f, 0.f, 0.f, 0.f};

    short8 aQ[2][2];
#pragma unroll
    for (int nt = 0; nt < 2; ++nt) {
        int n = w * 32 + nt * 16 + lrow;
#pragma unroll
        for (int s = 0; s < 2; ++s) {
            int g = (s * 4 + lquad) ^ (n & 7);
            aQ[nt][s] = *(const short8*)&Qs[n * 64 + g * 8];
        }
    }
#pragma unroll
    for (int mt = 0; mt < 8; ++mt) {
        int m = mt * 16 + lrow;
#pragma unroll
        for (int s = 0; s < 2; ++s) {
            int g = (s * 4 + lquad) ^ (m & 7);
            short8 bK = *(const short8*)&Ks[m * 64 + g * 8];
#pragma unroll
            for (int nt = 0; nt < 2; ++nt)
                acc[nt][mt] = __builtin_amdgcn_mfma_f32_16x16x32_bf16(aQ[nt][s], bK, acc[nt][mt], 0, 0, 0);
        }
    }

    // ---- softmax over m (rows per (lquad, reg); cols across 16 lanes + 8 mt) ----
    float* attnp = attn + (size_t)bd * (NBLK * NBLK);
#pragma unroll
    for (int nt = 0; nt < 2; ++nt) {
        int nbase = w * 32 + nt * 16;
#pragma unroll
        for (int r = 0; r < 4; ++r) {
            int row = nbase + lquad * 4 + r;
            float pv[8];
            float mx = -1e30f;
#pragma unroll
            for (int mt = 0; mt < 8; ++mt) { pv[mt] = acc[nt][mt][r]; mx = fmaxf(mx, pv[mt]); }
#pragma unroll
            for (int msk = 1; msk < 16; msk <<= 1) mx = fmaxf(mx, __shfl_xor(mx, msk, 64));
            float sum = 0.f;
#pragma unroll
            for (int mt = 0; mt < 8; ++mt) {
                pv[mt] = exp2f((pv[mt] - mx) * 1.4426950408889634f);
                sum += pv[mt];
            }
#pragma unroll
            for (int msk = 1; msk < 16; msk <<= 1) sum += __shfl_xor(sum, msk, 64);
            float inv = 1.0f / sum;
#pragma unroll
            for (int mt = 0; mt < 8; ++mt) {
                float a = pv[mt] * inv;
                int m = mt * 16 + lrow;
                __builtin_nontemporal_store(a, attnp + (size_t)row * NBLK + m);
                int g = (m >> 3) ^ (row & 7);
                Ps[row * 128 + g * 8 + (m & 7)] = f2bf(a);
            }
        }
    }
    // no barrier: PV below reads only rows n = w*32+nt*16+lrow (wave-private),
    // and same-wave ds_write->ds_read ordering is handled by lgkmcnt.

    // ---- O = A V' : [128 n x 64 p], K over m=128 ----
    f32x4 oacc[2][4];
#pragma unroll
    for (int nt = 0; nt < 2; ++nt)
#pragma unroll
        for (int pt = 0; pt < 4; ++pt) oacc[nt][pt] = (f32x4){0.f, 0.f, 0.f, 0.f};

#pragma unroll
    for (int s = 0; s < 4; ++s) {
        short8 aP[2];
#pragma unroll
        for (int nt = 0; nt < 2; ++nt) {
            int n = w * 32 + nt * 16 + lrow;
            int g = (s * 4 + lquad) ^ (n & 7);
            aP[nt] = *(const short8*)&Ps[n * 128 + g * 8];
        }
#pragma unroll
        for (int pt = 0; pt < 4; ++pt) {
            int prow = pt * 16 + lrow;
            int gv = (s * 4 + lquad) ^ (prow & 7);
            short8 bV = *(const short8*)&Vs[prow * 128 + gv * 8];
#pragma unroll
            for (int nt = 0; nt < 2; ++nt)
                oacc[nt][pt] = __builtin_amdgcn_mfma_f32_16x16x32_bf16(aP[nt], bV, oacc[nt][pt], 0, 0, 0);
        }
    }

    ushort_t* op = outT + base;
#pragma unroll
    for (int nt = 0; nt < 2; ++nt)
#pragma unroll
        for (int pt = 0; pt < 4; ++pt)
#pragma unroll
            for (int r = 0; r < 4; ++r) {
                int row = w * 32 + nt * 16 + lquad * 4 + r;
                int p = pt * 16 + lrow;
                op[row * PER + p] = f2bf(oacc[nt][pt][r]);  // cached: read by ko
            }
}

// ---- K_o: outT [B,D,L] bf16 -> out [B,L,D] fp32, LDS-free -----------------
// Thread subtile: 4 d x 4 l. Loads 8B bf16 rows; stores f32x4 rows.
__global__ __launch_bounds__(256) void ko(const ushort_t* __restrict__ outT,
                                          float* __restrict__ out) {
    const int t = threadIdx.x;
    const int l0 = blockIdx.x * 64 + 4 * (t & 15);
    const int d0 = blockIdx.y * 64 + 4 * (t >> 4);
    const int b = blockIdx.z;
    const ushort_t* sp = outT + (size_t)b * DD * LSEQ;
    float* op = out + (size_t)b * LSEQ * DD;
    uint2v ld[4];
#pragma unroll
    for (int dd = 0; dd < 4; ++dd)
        ld[dd] = __builtin_nontemporal_load(
            (const uint2v*)(sp + (size_t)(d0 + dd) * LSEQ + l0));
#pragma unroll
    for (int j = 0; j < 4; ++j) {
        f32x4 o;
#pragma unroll
        for (int dd = 0; dd < 4; ++dd)
            o[dd] = bf2f((ushort_t)((ld[dd][j >> 1] >> ((j & 1) * 16)) & 0xffffu));
        __builtin_nontemporal_store(o, (f32x4*)(op + (size_t)(l0 + j) * DD + d0));
    }
}

extern "C" void kernel_launch(void* const* d_in, const int* in_sizes, int n_in,
                              void* d_out, int out_size, void* d_ws, size_t ws_size,
                              hipStream_t stream) {
    const float* q = (const float*)d_in[0];
    const float* k = (const float*)d_in[1];
    const float* v = (const float*)d_in[2];
    float* outp = (float*)d_out;
    float* attnp = outp + (size_t)BB * LSEQ * DD;

    ushort_t* qT  = (ushort_t*)d_ws;
    ushort_t* kT  = qT  + (size_t)BB * DD * LSEQ;
    ushort_t* vTT = kT  + (size_t)BB * DD * LSEQ;
    ushort_t* oT  = vTT + (size_t)BB * DD * LSEQ;

    dim3 g1(LSEQ / 64, DD / 64, BB * 2);
    kt1<<<g1, 256, 0, stream>>>(q, k, qT, kT);
    dim3 g2(2 * PER, DD / 64, BB);
    kt2<<<g2, 256, 0, stream>>>(v, vTT);
    katt<<<dim3(BB * DD), 256, 0, stream>>>(qT, kT, vTT, attnp, oT);
    dim3 g3(LSEQ / 64, DD / 64, BB);
    ko<<<g3, 256, 0, stream>>>(oT, outp);
}

// Round 7
// 494.320 us; speedup vs baseline: 1.1638x; 1.0355x over previous
//
#include <hip/hip_runtime.h>
#include <stdint.h>

#define BB 16
#define LSEQ 8192
#define DD 512
#define PER 64
#define NBLK 128
#define QSCALE 0.45f

typedef __attribute__((ext_vector_type(8))) short short8;
typedef __attribute__((ext_vector_type(4))) float f32x4;
typedef __attribute__((ext_vector_type(2))) unsigned int uint2v;
typedef unsigned short ushort_t;

__device__ __forceinline__ ushort_t f2bf(float f) {
    union { float f; uint32_t u; } c; c.f = f;
    uint32_t u = c.u + 0x7FFFu + ((c.u >> 16) & 1u);
    return (ushort_t)(u >> 16);
}
__device__ __forceinline__ float bf2f(ushort_t h) {
    union { float f; uint32_t u; } c; c.u = ((uint32_t)h) << 16;
    return c.f;
}
__device__ __forceinline__ uint32_t pk2(float a, float b) {
    return (uint32_t)f2bf(a) | ((uint32_t)f2bf(b) << 16);
}

// ---- K_tr: merged q/k/v transposes, LDS-free 4x4 register subtiles ---------
// z 0..15: q -> qT [B,D,L] (scaled); 16..31: k -> kT; 32..47: v -> vTT.
__global__ __launch_bounds__(256) void ktr(const float* __restrict__ q,
                                           const float* __restrict__ k,
                                           const float* __restrict__ v,
                                           ushort_t* __restrict__ qT,
                                           ushort_t* __restrict__ kT,
                                           ushort_t* __restrict__ vTT) {
    const int t = threadIdx.x;
    const int zz = blockIdx.z;
    const int role = zz >> 4;  // 0=q, 1=k, 2=v
    const int b = zz & (BB - 1);
    if (role < 2) {
        const float scale = role ? 1.0f : QSCALE;
        const float* sp = (role ? k : q) + (size_t)b * LSEQ * DD;
        ushort_t* dp = (role ? kT : qT) + (size_t)b * DD * LSEQ;
        const int l0 = blockIdx.x * 64 + 4 * (t & 15);
        const int d0 = blockIdx.y * 64 + 4 * (t >> 4);
        f32x4 vv[4];
#pragma unroll
        for (int j = 0; j < 4; ++j)
            vv[j] = __builtin_nontemporal_load(
                (const f32x4*)(sp + (size_t)(l0 + j) * DD + d0));
#pragma unroll
        for (int dj = 0; dj < 4; ++dj) {
            uint2v w;
            w[0] = pk2(vv[0][dj] * scale, vv[1][dj] * scale);
            w[1] = pk2(vv[2][dj] * scale, vv[3][dj] * scale);
            *(uint2v*)(dp + (size_t)(d0 + dj) * LSEQ + l0) = w;  // cached: katt reads
        }
    } else {
        // v: vtt[((b*D+d)*PER+p)*NBLK+m] = v[b, m*64+p, d]
        const int p = blockIdx.x & 63;
        const int mh = blockIdx.x >> 6;  // 0..1
        const int m0 = mh * 64 + 4 * (t & 15);
        const int d0 = blockIdx.y * 64 + 4 * (t >> 4);
        const float* vp = v + (size_t)b * LSEQ * DD;
        f32x4 x[4];
#pragma unroll
        for (int mj = 0; mj < 4; ++mj)
            x[mj] = __builtin_nontemporal_load(
                (const f32x4*)(vp + (size_t)((m0 + mj) * PER + p) * DD + d0));
#pragma unroll
        for (int dj = 0; dj < 4; ++dj) {
            uint2v w;
            w[0] = pk2(x[0][dj], x[1][dj]);
            w[1] = pk2(x[2][dj], x[3][dj]);
            *(uint2v*)(vTT + (size_t)((size_t)(b * DD + d0 + dj) * PER + p) * NBLK + m0) = w;
        }
    }
}

// ---------------- K_att: per-(b,d) attention with MFMA ----------------------
// LDS (48 KB total, 3 blocks/CU):
//   Qs [128][64] @ sm+0, Ks [128][64] @ sm+8192  — dead after QK phase
//   Ps [128][128] OVERLAYS Qs+Ks (barrier between QK reads and Ps writes)
//   Vs [64][128] @ sm+16384
// XOR swizzle: granule' = granule ^ (row & 7)
__global__ __launch_bounds__(256, 3) void katt(const ushort_t* __restrict__ qT,
                                               const ushort_t* __restrict__ kT,
                                               const ushort_t* __restrict__ vTT,
                                               float* __restrict__ attn,
                                               ushort_t* __restrict__ outT) {
    __shared__ __align__(16) ushort_t sm[24576];
    ushort_t* Qs = sm;
    ushort_t* Ks = sm + 8192;
    ushort_t* Ps = sm;          // overlays Qs+Ks after QK phase
    ushort_t* Vs = sm + 16384;

    const int t = threadIdx.x;
    const int bd = blockIdx.x;
    const size_t base = (size_t)bd * 8192;
    const ushort_t* qp = qT + base;
    const ushort_t* kp = kT + base;
    const ushort_t* vp = vTT + base;

    // stage Q, K, V tiles (swizzled)
#pragma unroll
    for (int it = 0; it < 4; ++it) {
        int e = it * 2048 + t * 8;
        int n = e >> 6, pc = (e >> 3) & 7;
        int gq = pc ^ (n & 7);
        *(short8*)&Qs[n * 64 + gq * 8] = __builtin_nontemporal_load((const short8*)(qp + e));
        *(short8*)&Ks[n * 64 + gq * 8] = __builtin_nontemporal_load((const short8*)(kp + e));
        int p = e >> 7, mc = (e >> 3) & 15;
        int gv = mc ^ (p & 7);
        *(short8*)&Vs[p * 128 + gv * 8] = __builtin_nontemporal_load((const short8*)(vp + e));
    }
    __syncthreads();

    const int lane = t & 63, w = t >> 6;
    const int lrow = lane & 15, lquad = lane >> 4;

    // ---- S = Q' K'^T : rows n in [w*32, w*32+32) ----
    f32x4 acc[2][8];
#pragma unroll
    for (int nt = 0; nt < 2; ++nt)
#pragma unroll
        for (int mt = 0; mt < 8; ++mt) acc[nt][mt] = (f32x4){0.f, 0.f, 0.f, 0.f};

    short8 aQ[2][2];
#pragma unroll
    for (int nt = 0; nt < 2; ++nt) {
        int n = w * 32 + nt * 16 + lrow;
#pragma unroll
        for (int s = 0; s < 2; ++s) {
            int g = (s * 4 + lquad) ^ (n & 7);
            aQ[nt][s] = *(const short8*)&Qs[n * 64 + g * 8];
        }
    }
#pragma unroll
    for (int mt = 0; mt < 8; ++mt) {
        int m = mt * 16 + lrow;
#pragma unroll
        for (int s = 0; s < 2; ++s) {
            int g = (s * 4 + lquad) ^ (m & 7);
            short8 bK = *(const short8*)&Ks[m * 64 + g * 8];
#pragma unroll
            for (int nt = 0; nt < 2; ++nt)
                acc[nt][mt] = __builtin_amdgcn_mfma_f32_16x16x32_bf16(aQ[nt][s], bK, acc[nt][mt], 0, 0, 0);
        }
    }
    __syncthreads();  // all waves done reading Qs/Ks; Ps may now overwrite them

    // ---- softmax over m (rows per (lquad, reg); cols across 16 lanes + 8 mt) ----
    float* attnp = attn + (size_t)bd * (NBLK * NBLK);
#pragma unroll
    for (int nt = 0; nt < 2; ++nt) {
        int nbase = w * 32 + nt * 16;
#pragma unroll
        for (int r = 0; r < 4; ++r) {
            int row = nbase + lquad * 4 + r;
            float pv[8];
            float mx = -1e30f;
#pragma unroll
            for (int mt = 0; mt < 8; ++mt) { pv[mt] = acc[nt][mt][r]; mx = fmaxf(mx, pv[mt]); }
#pragma unroll
            for (int msk = 1; msk < 16; msk <<= 1) mx = fmaxf(mx, __shfl_xor(mx, msk, 64));
            float sum = 0.f;
#pragma unroll
            for (int mt = 0; mt < 8; ++mt) {
                pv[mt] = exp2f((pv[mt] - mx) * 1.4426950408889634f);
                sum += pv[mt];
            }
#pragma unroll
            for (int msk = 1; msk < 16; msk <<= 1) sum += __shfl_xor(sum, msk, 64);
            float inv = 1.0f / sum;
#pragma unroll
            for (int mt = 0; mt < 8; ++mt) {
                float a = pv[mt] * inv;
                int m = mt * 16 + lrow;
                __builtin_nontemporal_store(a, attnp + (size_t)row * NBLK + m);
                int g = (m >> 3) ^ (row & 7);
                Ps[row * 128 + g * 8 + (m & 7)] = f2bf(a);
            }
        }
    }
    // no barrier: PV reads only this wave's Ps rows (wave-private);
    // same-wave ds ordering is handled by lgkmcnt.

    // ---- O = A V' : [128 n x 64 p], K over m=128 ----
    f32x4 oacc[2][4];
#pragma unroll
    for (int nt = 0; nt < 2; ++nt)
#pragma unroll
        for (int pt = 0; pt < 4; ++pt) oacc[nt][pt] = (f32x4){0.f, 0.f, 0.f, 0.f};

#pragma unroll
    for (int s = 0; s < 4; ++s) {
        short8 aP[2];
#pragma unroll
        for (int nt = 0; nt < 2; ++nt) {
            int n = w * 32 + nt * 16 + lrow;
            int g = (s * 4 + lquad) ^ (n & 7);
            aP[nt] = *(const short8*)&Ps[n * 128 + g * 8];
        }
#pragma unroll
        for (int pt = 0; pt < 4; ++pt) {
            int prow = pt * 16 + lrow;
            int gv = (s * 4 + lquad) ^ (prow & 7);
            short8 bV = *(const short8*)&Vs[prow * 128 + gv * 8];
#pragma unroll
            for (int nt = 0; nt < 2; ++nt)
                oacc[nt][pt] = __builtin_amdgcn_mfma_f32_16x16x32_bf16(aP[nt], bV, oacc[nt][pt], 0, 0, 0);
        }
    }

    ushort_t* op = outT + base;
#pragma unroll
    for (int nt = 0; nt < 2; ++nt)
#pragma unroll
        for (int pt = 0; pt < 4; ++pt)
#pragma unroll
            for (int r = 0; r < 4; ++r) {
                int row = w * 32 + nt * 16 + lquad * 4 + r;
                int p = pt * 16 + lrow;
                op[row * PER + p] = f2bf(oacc[nt][pt][r]);  // cached: read by ko
            }
}

// ---- K_o: outT [B,D,L] bf16 -> out [B,L,D] fp32, LDS-free -----------------
__global__ __launch_bounds__(256) void ko(const ushort_t* __restrict__ outT,
                                          float* __restrict__ out) {
    const int t = threadIdx.x;
    const int l0 = blockIdx.x * 64 + 4 * (t & 15);
    const int d0 = blockIdx.y * 64 + 4 * (t >> 4);
    const int b = blockIdx.z;
    const ushort_t* sp = outT + (size_t)b * DD * LSEQ;
    float* op = out + (size_t)b * LSEQ * DD;
    uint2v ld[4];
#pragma unroll
    for (int dd = 0; dd < 4; ++dd)
        ld[dd] = __builtin_nontemporal_load(
            (const uint2v*)(sp + (size_t)(d0 + dd) * LSEQ + l0));
#pragma unroll
    for (int j = 0; j < 4; ++j) {
        f32x4 o;
#pragma unroll
        for (int dd = 0; dd < 4; ++dd)
            o[dd] = bf2f((ushort_t)((ld[dd][j >> 1] >> ((j & 1) * 16)) & 0xffffu));
        __builtin_nontemporal_store(o, (f32x4*)(op + (size_t)(l0 + j) * DD + d0));
    }
}

extern "C" void kernel_launch(void* const* d_in, const int* in_sizes, int n_in,
                              void* d_out, int out_size, void* d_ws, size_t ws_size,
                              hipStream_t stream) {
    const float* q = (const float*)d_in[0];
    const float* k = (const float*)d_in[1];
    const float* v = (const float*)d_in[2];
    float* outp = (float*)d_out;
    float* attnp = outp + (size_t)BB * LSEQ * DD;

    ushort_t* qT  = (ushort_t*)d_ws;
    ushort_t* kT  = qT  + (size_t)BB * DD * LSEQ;
    ushort_t* vTT = kT  + (size_t)BB * DD * LSEQ;
    ushort_t* oT  = vTT + (size_t)BB * DD * LSEQ;

    dim3 g1(LSEQ / 64, DD / 64, BB * 3);
    ktr<<<g1, 256, 0, stream>>>(q, k, v, qT, kT, vTT);
    katt<<<dim3(BB * DD), 256, 0, stream>>>(qT, kT, vTT, attnp, oT);
    dim3 g3(LSEQ / 64, DD / 64, BB);
    ko<<<g3, 256, 0, stream>>>(oT, outp);
}